// Round 9
// baseline (74.347 us; speedup 1.0000x reference)
//
#include <hip/hip_runtime.h>

// Per-channel histogram: in [LENGTH=1e6, C=64] int32 values in [0,256),
// out [64, 256] int32 counts. 256 MB read.
//
// R9 = R8 with the HADD bug fixed. R8's increment was
//   1u + ((v&1)<<16)   -> odd values bumped BOTH half-words (even bins 2x).
// Correct: 1u << ((v&1)*16) -> exactly one u16 counter per value.
//
// Probe config (unchanged from R8): 24 waves/CU (768 blocks x 512 thr,
// 3 blocks/CU, 1536 thr/CU - under the 2048/CU cliff R7 hit). Histogram
// packed 2 x u16 per u32 word (32 KB/hist, 96 KB/CU): word = ch*128+(v>>1).
// Per-block per-halfword counts <= ~30 << 65535, no carry. Flush: word jj
// holds bins (2k,2k+1) as u16 lo/hi; out u32 index of bin 2k is 2*jj ->
// one u64 atomic: lo + (hi<<32).

#define NCH   64
#define NBINS 256
#define NWORDS (NCH * NBINS / 2)   // 8192 u32 words = 32 KB LDS
#define THREADS 512
#define BLOCKS  768                // 3 blocks/CU, 24 waves/CU

__global__ __launch_bounds__(THREADS) void hist_kernel(
    const int* __restrict__ in, unsigned long long* __restrict__ out,
    long long n4)
{
    __shared__ unsigned int hist[NWORDS];
    const int tid = threadIdx.x;

    #pragma unroll
    for (int k = 0; k < NWORDS / THREADS; ++k)
        hist[tid + k * THREADS] = 0u;
    __syncthreads();

    const int4* __restrict__ in4 = (const int4*)in;

    // Contiguous per-block segment [seg0, seg_end).
    const long long per_block = (n4 + BLOCKS - 1) / BLOCKS;   // 20834
    const long long seg0 = (long long)blockIdx.x * per_block;
    const long long seg_end = (seg0 + per_block < n4) ? (seg0 + per_block) : n4;
    const int seg_len = (int)(seg_end > seg0 ? seg_end - seg0 : 0);

    // int4 m covers flat ints [4m,4m+4) -> channels (m&15)*4..+3.
    // All loop steps are multiples of 512 (512%16==0) -> per-thread const.
    const int c0 = (int)(((seg0 + tid) & 15) << 2);
    unsigned int* __restrict__ h = &hist[c0 * (NBINS / 2)];

    const int4* __restrict__ base = in4 + seg0;

    // One value -> one u32 atomic on word (choff*128 + (v>>1)):
    // even v adds 1 (low u16), odd v adds 1<<16 (high u16). Never both.
    #define HADD(choff, v) \
        atomicAdd(&h[(choff) * (NBINS / 2) + ((v) >> 1)], \
                  1u << ((((unsigned)(v)) & 1u) << 4))

    // Depth-2 main loop: block reads 2x8KB contiguous per iteration.
    const int full2 = seg_len / (2 * THREADS);
    for (int k = 0; k < full2; ++k) {
        const int j = k * 2 * THREADS + tid;
        int4 a = base[j];
        int4 b = base[j + THREADS];
        HADD(0, a.x); HADD(1, a.y); HADD(2, a.z); HADD(3, a.w);
        HADD(0, b.x); HADD(1, b.y); HADD(2, b.z); HADD(3, b.w);
    }
    // Tail (steps stay multiples of THREADS -> channel base unchanged).
    int j = full2 * 2 * THREADS + tid;
    if (j < seg_len) {
        int4 a = base[j];
        HADD(0, a.x); HADD(1, a.y); HADD(2, a.z); HADD(3, a.w);
    }
    j += THREADS;
    if (j < seg_len) {
        int4 a = base[j];
        HADD(0, a.x); HADD(1, a.y); HADD(2, a.z); HADD(3, a.w);
    }
    #undef HADD
    __syncthreads();

    // Flush: word jj (bins 2k,2k+1 of ch, u16 lo/hi) -> out64[jj] with
    // value lo + (hi<<32). Rotate start offset per block to spread L2 lines.
    #pragma unroll
    for (int kk = 0; kk < NWORDS / THREADS; ++kk) {
        const int jj = (tid + kk * THREADS + blockIdx.x * 32) & (NWORDS - 1);
        const unsigned int w = hist[jj];
        if (w) {
            const unsigned long long v =
                (unsigned long long)(w & 0xFFFFu) |
                ((unsigned long long)(w >> 16) << 32);
            atomicAdd(&out[jj], v);
        }
    }
}

extern "C" void kernel_launch(void* const* d_in, const int* in_sizes, int n_in,
                              void* d_out, int out_size, void* d_ws, size_t ws_size,
                              hipStream_t stream) {
    const int* in = (const int*)d_in[0];
    unsigned long long* out = (unsigned long long*)d_out;
    const long long n = (long long)in_sizes[0];   // 64,000,000 (divisible by 4)
    const long long n4 = n / 4;

    // Replays accumulate via atomics -> must zero the output every launch.
    hipMemsetAsync(d_out, 0, (size_t)out_size * sizeof(int), stream);

    hist_kernel<<<BLOCKS, THREADS, 0, stream>>>(in, out, n4);
}